// Round 1
// baseline (1033.070 us; speedup 1.0000x reference)
//
#include <hip/hip_runtime.h>
#include <hip/hip_bf16.h>
#include <stdint.h>

typedef __attribute__((ext_vector_type(8))) short short8;
typedef __attribute__((ext_vector_type(4))) float f32x4;

#define QMAXF 255.0f

constexpr int Bb = 4, Ss = 1024, Ee = 1024, Hh = 16, Dd = 64;
constexpr int Mm = Bb * Ss;   // 4096
constexpr int F3 = 3 * Ee;    // 3072
constexpr int Kk = Ee;        // 1024

// our quantized values are integers with |v| <= 255+ -> exactly representable in
// bf16, so the bf16 bits are just the top 16 bits of the fp32 pattern.
__device__ __forceinline__ unsigned short f2bf_exact(float f) {
    return (unsigned short)(__float_as_uint(f) >> 16);
}

// per-tensor activation fake-quant -> integer-valued bf16 (q - zp)
__global__ void quant_act(const float* __restrict__ x, unsigned short* __restrict__ out,
                          const float* __restrict__ sp, const float* __restrict__ zpp, int n) {
    float s = sp[0], zp = zpp[0];
    for (int i = blockIdx.x * blockDim.x + threadIdx.x; i < n; i += gridDim.x * blockDim.x) {
        float q = x[i] / s + zp;
        q = fminf(fmaxf(q, 0.0f), QMAXF);
        out[i] = f2bf_exact(rintf(q) - zp);
    }
}

// per-row (out-channel) weight fake-quant, row length 1024
__global__ void quant_w(const float* __restrict__ W, unsigned short* __restrict__ out,
                        const float* __restrict__ sv, const float* __restrict__ zv, int n) {
    for (int i = blockIdx.x * blockDim.x + threadIdx.x; i < n; i += gridDim.x * blockDim.x) {
        int r = i >> 10;
        float s = sv[r], zp = zv[r];
        float q = W[i] / s + zp;
        q = fminf(fmaxf(q, 0.0f), QMAXF);
        out[i] = f2bf_exact(rintf(q) - zp);
    }
}

// C[m][n] = s_a*s_w[n]*sum_k A[m][k]*Bw[n][k] + bias[n]
// A [M][1024], Bw [N][1024] both bf16-bit integer-valued -> MFMA accumulation exact.
// MODE 0: scatter into q/k/v [B,H,S,D]; MODE 1: write [M][1024] to o0.
template<int MODE>
__global__ __launch_bounds__(256)
void gemm_fq(const unsigned short* __restrict__ A,
             const unsigned short* __restrict__ Bw,
             const float* __restrict__ sa_p,
             const float* __restrict__ sw_v,
             const float* __restrict__ bias_v,
             float* __restrict__ o0, float* __restrict__ o1, float* __restrict__ o2,
             int ntiles) {
    __shared__ unsigned short At[128][32];
    __shared__ unsigned short Bt[128][32];
    const int t = threadIdx.x;
    const int tile_m = (blockIdx.x / ntiles) * 128;
    const int tile_n = (blockIdx.x % ntiles) * 128;
    const int lane = t & 63, wid = t >> 6;
    const int wr = wid >> 1, wc = wid & 1;
    const int srow = t >> 1, scol = (t & 1) * 16;
    const float sa = sa_p[0];

    const unsigned short* ga = A + (size_t)(tile_m + srow) * Kk + scol;
    const unsigned short* gb = Bw + (size_t)(tile_n + srow) * Kk + scol;

    const f32x4 zero4 = {0.f, 0.f, 0.f, 0.f};
    f32x4 acc[4][4];
    #pragma unroll
    for (int i = 0; i < 4; ++i)
        #pragma unroll
        for (int j = 0; j < 4; ++j) acc[i][j] = zero4;

    short8 ra0 = *(const short8*)(ga);
    short8 ra1 = *(const short8*)(ga + 8);
    short8 rb0 = *(const short8*)(gb);
    short8 rb1 = *(const short8*)(gb + 8);

    const int NKT = Kk / 32;
    for (int kt = 0; kt < NKT; ++kt) {
        __syncthreads();
        *(short8*)&At[srow][scol]     = ra0;
        *(short8*)&At[srow][scol + 8] = ra1;
        *(short8*)&Bt[srow][scol]     = rb0;
        *(short8*)&Bt[srow][scol + 8] = rb1;
        __syncthreads();
        // prefetch next K-slab while MFMAs run
        int kn = (kt + 1 < NKT) ? (kt + 1) * 32 : kt * 32;
        ra0 = *(const short8*)(ga + kn);
        ra1 = *(const short8*)(ga + kn + 8);
        rb0 = *(const short8*)(gb + kn);
        rb1 = *(const short8*)(gb + kn + 8);

        const int kq = (lane >> 4) * 8;
        const int rowA = wr * 64 + (lane & 15);
        const int rowB = wc * 64 + (lane & 15);
        short8 af[4], bfr[4];
        #pragma unroll
        for (int i = 0; i < 4; ++i) af[i] = *(const short8*)&At[rowA + i * 16][kq];
        #pragma unroll
        for (int j = 0; j < 4; ++j) bfr[j] = *(const short8*)&Bt[rowB + j * 16][kq];
        #pragma unroll
        for (int i = 0; i < 4; ++i)
            #pragma unroll
            for (int j = 0; j < 4; ++j)
                acc[i][j] = __builtin_amdgcn_mfma_f32_16x16x32_bf16(af[i], bfr[j], acc[i][j], 0, 0, 0);
    }

    // C/D layout: col = lane&15, row = (lane>>4)*4 + reg   [m89]
    const int lr4 = (lane >> 4) * 4;
    const int lc = lane & 15;
    #pragma unroll
    for (int j = 0; j < 4; ++j) {
        int n = tile_n + wc * 64 + j * 16 + lc;
        float sw = sw_v[n] * sa;
        float bv = bias_v[n];
        #pragma unroll
        for (int i = 0; i < 4; ++i) {
            int mbase = tile_m + wr * 64 + i * 16 + lr4;
            #pragma unroll
            for (int r = 0; r < 4; ++r) {
                int m = mbase + r;
                float val = acc[i][j][r] * sw + bv;
                if (MODE == 0) {
                    int which = n >> 10, h = (n >> 6) & 15, d = n & 63;
                    int bi = m >> 10, si = m & 1023;
                    float* dst = (which == 0) ? o0 : (which == 1) ? o1 : o2;
                    dst[(((size_t)(bi * Hh + h)) * Ss + si) * Dd + d] = val;
                } else {
                    o0[(size_t)m * Ee + n] = val;
                }
            }
        }
    }
}

// fp32 flash attention over fake-quantized scores, fused proj-activation quant.
// block: one (b,h) x 64 query rows; thread t -> (row t/4, key-stripe t%4).
__global__ __launch_bounds__(256)
void attn_fused(const float* __restrict__ qb, const float* __restrict__ kb, const float* __restrict__ vb,
                const float* __restrict__ s_at_p, const float* __restrict__ zp_at_p,
                const float* __restrict__ s_ap_p, const float* __restrict__ zp_ap_p,
                unsigned short* __restrict__ outq) {
    __shared__ float Kt[128][64];
    __shared__ float Vt[128][64];
    const int t = threadIdx.x;
    const int bh = blockIdx.x >> 4;
    const int qt = blockIdx.x & 15;
    const int r = t >> 2, kg = t & 3;
    const int qrow = qt * 64 + r;
    const float s_at = s_at_p[0], zp_at = zp_at_p[0];
    const float s_ap = s_ap_p[0], zp_ap = zp_ap_p[0];
    const float* qrow_ptr = qb + ((size_t)bh * Ss + qrow) * Dd;
    const float* kbase = kb + (size_t)bh * Ss * Dd;
    const float* vbase = vb + (size_t)bh * Ss * Dd;

    f32x4 q4[16], o4[16];
    #pragma unroll
    for (int i = 0; i < 16; ++i) q4[i] = ((const f32x4*)qrow_ptr)[i];
    #pragma unroll
    for (int i = 0; i < 16; ++i) o4[i] = (f32x4){0.f, 0.f, 0.f, 0.f};
    float m_run = -1e30f, l_run = 0.0f;

    for (int tile = 0; tile < 8; ++tile) {
        __syncthreads();
        const f32x4* ks = (const f32x4*)(kbase + (size_t)tile * 128 * 64);
        const f32x4* vs = (const f32x4*)(vbase + (size_t)tile * 128 * 64);
        f32x4* kd = (f32x4*)&Kt[0][0];
        f32x4* vd = (f32x4*)&Vt[0][0];
        #pragma unroll
        for (int i = 0; i < 8; ++i) kd[t + i * 256] = ks[t + i * 256];
        #pragma unroll
        for (int i = 0; i < 8; ++i) vd[t + i * 256] = vs[t + i * 256];
        __syncthreads();

        float p[32];
        float mloc = m_run;
        #pragma unroll
        for (int j = 0; j < 32; ++j) {
            const f32x4* krow = (const f32x4*)&Kt[kg * 32 + j][0];
            f32x4 d4 = {0.f, 0.f, 0.f, 0.f};
            #pragma unroll
            for (int i = 0; i < 16; ++i) d4 = d4 + q4[i] * krow[i];
            float sc = ((d4[0] + d4[1]) + (d4[2] + d4[3])) * 0.125f;  // /sqrt(64), exact
            float qv = sc / s_at + zp_at;
            qv = fminf(fmaxf(qv, 0.0f), QMAXF);
            sc = (rintf(qv) - zp_at) * s_at;   // fake-quant score (rint = round-half-even)
            p[j] = sc;
            mloc = fmaxf(mloc, sc);
        }
        float resc = __expf(m_run - mloc);
        l_run *= resc;
        #pragma unroll
        for (int i = 0; i < 16; ++i) o4[i] = o4[i] * resc;
        m_run = mloc;
        #pragma unroll
        for (int j = 0; j < 32; ++j) {
            float pj = __expf(p[j] - m_run);
            l_run += pj;
            const f32x4* vrow = (const f32x4*)&Vt[kg * 32 + j][0];
            #pragma unroll
            for (int i = 0; i < 16; ++i) o4[i] = o4[i] + vrow[i] * pj;
        }
    }

    // merge 4 key-stripe threads (contiguous lanes) per row
    #pragma unroll
    for (int off = 1; off <= 2; off <<= 1) {
        float m_o = __shfl_xor(m_run, off);
        float l_o = __shfl_xor(l_run, off);
        float m_n = fmaxf(m_run, m_o);
        float ea = __expf(m_run - m_n), eb = __expf(m_o - m_n);
        l_run = l_run * ea + l_o * eb;
        #pragma unroll
        for (int i = 0; i < 16; ++i) {
            f32x4 oo;
            #pragma unroll
            for (int c = 0; c < 4; ++c) oo[c] = __shfl_xor(o4[i][c], off);
            #pragma unroll
            for (int c = 0; c < 4; ++c) o4[i][c] = o4[i][c] * ea + oo[c] * eb;
        }
        m_run = m_n;
    }

    if (kg == 0) {
        float inv_l = 1.0f / l_run;
        const int b = bh >> 4, h = bh & 15;
        unsigned short* dst = outq + ((size_t)(b * Ss + qrow)) * Ee + h * Dd;
        #pragma unroll
        for (int i = 0; i < 16; ++i) {
            #pragma unroll
            for (int c = 0; c < 4; ++c) {
                float ov = o4[i][c] * inv_l;
                float qv = ov / s_ap + zp_ap;
                qv = fminf(fmaxf(qv, 0.0f), QMAXF);
                dst[i * 4 + c] = f2bf_exact(rintf(qv) - zp_ap);  // proj-activation quant fused
            }
        }
    }
}

extern "C" void kernel_launch(void* const* d_in, const int* in_sizes, int n_in,
                              void* d_out, int out_size, void* d_ws, size_t ws_size,
                              hipStream_t stream) {
    const float* x           = (const float*)d_in[0];
    const float* W_qkv       = (const float*)d_in[1];
    const float* b_qkv       = (const float*)d_in[2];
    const float* W_proj      = (const float*)d_in[3];
    const float* b_proj      = (const float*)d_in[4];
    const float* s_act_qkv   = (const float*)d_in[5];
    const float* zp_act_qkv  = (const float*)d_in[6];
    const float* s_w_qkv     = (const float*)d_in[7];
    const float* zp_w_qkv    = (const float*)d_in[8];
    const float* s_attn      = (const float*)d_in[9];
    const float* zp_attn     = (const float*)d_in[10];
    const float* s_act_proj  = (const float*)d_in[11];
    const float* zp_act_proj = (const float*)d_in[12];
    const float* s_w_proj    = (const float*)d_in[13];
    const float* zp_w_proj   = (const float*)d_in[14];

    // workspace layout (72 MB total)
    char* ws = (char*)d_ws;
    unsigned short* xq   = (unsigned short*)(ws);                        // 8 MB
    unsigned short* wqq  = (unsigned short*)(ws + ((size_t)8 << 20));    // 6 MB
    unsigned short* wpq  = (unsigned short*)(ws + ((size_t)14 << 20));   // 2 MB
    float* qb            = (float*)(ws + ((size_t)16 << 20));            // 16 MB
    float* kb            = (float*)(ws + ((size_t)32 << 20));            // 16 MB
    float* vb            = (float*)(ws + ((size_t)48 << 20));            // 16 MB
    unsigned short* outq = (unsigned short*)(ws + ((size_t)64 << 20));   // 8 MB

    quant_act<<<1024, 256, 0, stream>>>(x, xq, s_act_qkv, zp_act_qkv, Mm * Ee);
    quant_w<<<768, 256, 0, stream>>>(W_qkv, wqq, s_w_qkv, zp_w_qkv, F3 * Ee);
    quant_w<<<256, 256, 0, stream>>>(W_proj, wpq, s_w_proj, zp_w_proj, Ee * Ee);
    gemm_fq<0><<<768, 256, 0, stream>>>(xq, wqq, s_act_qkv, s_w_qkv, b_qkv, qb, kb, vb, 24);
    attn_fused<<<1024, 256, 0, stream>>>(qb, kb, vb, s_attn, zp_attn, s_act_proj, zp_act_proj, outq);
    gemm_fq<1><<<256, 256, 0, stream>>>(outq, wpq, s_act_proj, s_w_proj, b_proj, (float*)d_out,
                                        nullptr, nullptr, 8);
}

// Round 2
// 193.189 us; speedup vs baseline: 5.3475x; 5.3475x over previous
//
#include <hip/hip_runtime.h>
#include <hip/hip_bf16.h>
#include <stdint.h>

typedef __attribute__((ext_vector_type(8))) short short8;
typedef __attribute__((ext_vector_type(4))) float f32x4;
typedef __attribute__((ext_vector_type(16))) float f32x16;
typedef _Float16 f16x8 __attribute__((ext_vector_type(8)));
typedef _Float16 f16x4 __attribute__((ext_vector_type(4)));

#define QMAXF 255.0f

constexpr int Bb = 4, Ss = 1024, Ee = 1024, Hh = 16, Dd = 64;
constexpr int Mm = Bb * Ss;   // 4096
constexpr int F3 = 3 * Ee;    // 3072
constexpr int Kk = Ee;        // 1024

// quantized values are integers |v| <= 255 -> exact in bf16: top 16 bits of fp32.
__device__ __forceinline__ unsigned short f2bf_exact(float f) {
    return (unsigned short)(__float_as_uint(f) >> 16);
}

__global__ void quant_act(const float* __restrict__ x, unsigned short* __restrict__ out,
                          const float* __restrict__ sp, const float* __restrict__ zpp, int n) {
    float s = sp[0], zp = zpp[0];
    for (int i = blockIdx.x * blockDim.x + threadIdx.x; i < n; i += gridDim.x * blockDim.x) {
        float q = x[i] / s + zp;
        q = fminf(fmaxf(q, 0.0f), QMAXF);
        out[i] = f2bf_exact(rintf(q) - zp);
    }
}

__global__ void quant_w(const float* __restrict__ W, unsigned short* __restrict__ out,
                        const float* __restrict__ sv, const float* __restrict__ zv, int n) {
    for (int i = blockIdx.x * blockDim.x + threadIdx.x; i < n; i += gridDim.x * blockDim.x) {
        int r = i >> 10;
        float s = sv[r], zp = zv[r];
        float q = W[i] / s + zp;
        q = fminf(fmaxf(q, 0.0f), QMAXF);
        out[i] = f2bf_exact(rintf(q) - zp);
    }
}

// C[m][n] = s_a*s_w[n]*sum_k A[m][k]*Bw[n][k] + bias[n]  (bf16 integer MFMA, exact)
// MODE 0: write q,k as f16 hi/lo planes [B*H][S][D], v as fp32 [B*H][S][D]
// MODE 1: write [M][1024] fp32 to o0
template<int MODE>
__global__ __launch_bounds__(256)
void gemm_fq(const unsigned short* __restrict__ A,
             const unsigned short* __restrict__ Bw,
             const float* __restrict__ sa_p,
             const float* __restrict__ sw_v,
             const float* __restrict__ bias_v,
             float* __restrict__ o0,
             _Float16* __restrict__ qhp, _Float16* __restrict__ qlp,
             _Float16* __restrict__ khp, _Float16* __restrict__ klp,
             int ntiles) {
    __shared__ unsigned short At[128][32];
    __shared__ unsigned short Bt[128][32];
    const int t = threadIdx.x;
    const int tile_m = (blockIdx.x / ntiles) * 128;
    const int tile_n = (blockIdx.x % ntiles) * 128;
    const int lane = t & 63, wid = t >> 6;
    const int wr = wid >> 1, wc = wid & 1;
    const int srow = t >> 1, scol = (t & 1) * 16;
    const float sa = sa_p[0];

    const unsigned short* ga = A + (size_t)(tile_m + srow) * Kk + scol;
    const unsigned short* gb = Bw + (size_t)(tile_n + srow) * Kk + scol;

    f32x4 acc[4][4];
    #pragma unroll
    for (int i = 0; i < 4; ++i)
        #pragma unroll
        for (int j = 0; j < 4; ++j)
            #pragma unroll
            for (int e = 0; e < 4; ++e) acc[i][j][e] = 0.0f;

    short8 ra0 = *(const short8*)(ga);
    short8 ra1 = *(const short8*)(ga + 8);
    short8 rb0 = *(const short8*)(gb);
    short8 rb1 = *(const short8*)(gb + 8);

    const int NKT = Kk / 32;
    for (int kt = 0; kt < NKT; ++kt) {
        __syncthreads();
        *(short8*)&At[srow][scol]     = ra0;
        *(short8*)&At[srow][scol + 8] = ra1;
        *(short8*)&Bt[srow][scol]     = rb0;
        *(short8*)&Bt[srow][scol + 8] = rb1;
        __syncthreads();
        int kn = (kt + 1 < NKT) ? (kt + 1) * 32 : kt * 32;
        ra0 = *(const short8*)(ga + kn);
        ra1 = *(const short8*)(ga + kn + 8);
        rb0 = *(const short8*)(gb + kn);
        rb1 = *(const short8*)(gb + kn + 8);

        const int kq = (lane >> 4) * 8;
        const int rowA = wr * 64 + (lane & 15);
        const int rowB = wc * 64 + (lane & 15);
        short8 af[4], bfr[4];
        #pragma unroll
        for (int i = 0; i < 4; ++i) af[i] = *(const short8*)&At[rowA + i * 16][kq];
        #pragma unroll
        for (int j = 0; j < 4; ++j) bfr[j] = *(const short8*)&Bt[rowB + j * 16][kq];
        #pragma unroll
        for (int i = 0; i < 4; ++i)
            #pragma unroll
            for (int j = 0; j < 4; ++j)
                acc[i][j] = __builtin_amdgcn_mfma_f32_16x16x32_bf16(af[i], bfr[j], acc[i][j], 0, 0, 0);
    }

    const int lr4 = (lane >> 4) * 4;
    const int lc = lane & 15;
    #pragma unroll
    for (int j = 0; j < 4; ++j) {
        int n = tile_n + wc * 64 + j * 16 + lc;
        float sw = sw_v[n] * sa;
        float bv = bias_v[n];
        #pragma unroll
        for (int i = 0; i < 4; ++i) {
            int mbase = tile_m + wr * 64 + i * 16 + lr4;
            #pragma unroll
            for (int r = 0; r < 4; ++r) {
                int m = mbase + r;
                float val = acc[i][j][r] * sw + bv;
                if (MODE == 0) {
                    int which = n >> 10, hh = (n >> 6) & 15, d = n & 63;
                    int bi = m >> 10, si = m & 1023;
                    size_t idx = (((size_t)(bi * Hh + hh)) * Ss + si) * Dd + d;
                    if (which == 2) {
                        o0[idx] = val;
                    } else {
                        _Float16 hi = (_Float16)val;
                        _Float16 lo = (_Float16)(val - (float)hi);
                        if (which == 0) { qhp[idx] = hi; qlp[idx] = lo; }
                        else            { khp[idx] = hi; klp[idx] = lo; }
                    }
                } else {
                    o0[(size_t)m * Ee + n] = val;
                }
            }
        }
    }
}

// V [bh][s][64] fp32 -> V^T hi/lo f16 planes [bh][64][1024]
__global__ __launch_bounds__(256)
void vtrans(const float* __restrict__ vb, _Float16* __restrict__ vth, _Float16* __restrict__ vtl) {
    __shared__ float tile[64][65];
    const int t = threadIdx.x;
    const int bh = blockIdx.x >> 4, st = blockIdx.x & 15;
    {
        const int r = t >> 2, c0 = (t & 3) * 16;
        const float* src = vb + (((size_t)bh * Ss) + st * 64 + r) * Dd + c0;
        #pragma unroll
        for (int j = 0; j < 4; ++j) {
            f32x4 v = *(const f32x4*)(src + j * 4);
            tile[r][c0 + j * 4 + 0] = v[0];
            tile[r][c0 + j * 4 + 1] = v[1];
            tile[r][c0 + j * 4 + 2] = v[2];
            tile[r][c0 + j * 4 + 3] = v[3];
        }
    }
    __syncthreads();
    {
        const int d = t >> 2, s0 = (t & 3) * 16;
        f16x8 oh0, oh1, ol0, ol1;
        #pragma unroll
        for (int i = 0; i < 16; ++i) {
            float x = tile[s0 + i][d];
            _Float16 hi = (_Float16)x;
            _Float16 lo = (_Float16)(x - (float)hi);
            if (i < 8) { oh0[i] = hi; ol0[i] = lo; }
            else       { oh1[i - 8] = hi; ol1[i - 8] = lo; }
        }
        size_t base = (((size_t)bh * Dd) + d) * Ss + st * 64 + s0;
        *(f16x8*)(vth + base)     = oh0;
        *(f16x8*)(vth + base + 8) = oh1;
        *(f16x8*)(vtl + base)     = ol0;
        *(f16x8*)(vtl + base + 8) = ol1;
    }
}

// Fused flash attention, f16 hi/lo split MFMA (fp32-level accuracy).
// Block: 128 q-rows of one (b,h); 4 waves x 32q. 16 KV tiles of 64 keys.
__global__ __launch_bounds__(256, 2)
void attn_mfma(const _Float16* __restrict__ qhp, const _Float16* __restrict__ qlp,
               const _Float16* __restrict__ khp, const _Float16* __restrict__ klp,
               const _Float16* __restrict__ vth, const _Float16* __restrict__ vtl,
               const float* __restrict__ s_at_p, const float* __restrict__ zp_at_p,
               const float* __restrict__ s_ap_p, const float* __restrict__ zp_ap_p,
               unsigned short* __restrict__ outq) {
    __shared__ uint4 lds4[65536 / 16];
    char* lds = (char*)lds4;
    constexpr int KH_OFF = 0, KL_OFF = 8192, VH_OFF = 16384, VL_OFF = 24576, P_OFF = 32768;

    const int t = threadIdx.x;
    const int lane = t & 63;
    const int w = t >> 6;
    const int l31 = lane & 31;
    const int lhalf = lane >> 5;
    const int bh = blockIdx.x >> 3;
    const int qt = blockIdx.x & 7;
    const int b = bh >> 4, h = bh & 15;

    const float s_at = s_at_p[0], zp_at = zp_at_p[0];
    const float s_ap = s_ap_p[0], zp_ap = zp_ap_p[0];

    // Q fragments (MFMA B-operand): lane holds Q[q0+l31][ks*16 + lhalf*8 + 0..7]
    const int qrow = qt * 128 + w * 32 + l31;
    const size_t qbase = ((size_t)bh * Ss + qrow) * Dd;
    f16x8 Qh[4], Ql[4];
    #pragma unroll
    for (int ks = 0; ks < 4; ++ks) {
        int dd = ks * 16 + lhalf * 8;
        Qh[ks] = *(const f16x8*)(qhp + qbase + dd);
        Ql[ks] = *(const f16x8*)(qlp + qbase + dd);
    }

    f32x16 o0, o1;
    #pragma unroll
    for (int i = 0; i < 16; ++i) { o0[i] = 0.0f; o1[i] = 0.0f; }
    float m_run = -1e30f, l_run = 0.0f;

    // staging: thread t covers chunks {sch, sch+1} of row srow for each of 4 planes
    const int srow = (t * 2) >> 3;          // 0..63
    const int sch = (t * 2) & 7;            // 0,2,4,6
    const int swz0 = ((sch    ) ^ (srow & 7)) << 4;
    const int swz1 = ((sch + 1) ^ (srow & 7)) << 4;
    const size_t kgrow = ((size_t)bh * Ss + srow) * Dd + sch * 8;   // + kbase*64
    const size_t vgrow = ((size_t)bh * Dd + srow) * Ss + sch * 8;   // + kbase

    for (int tile = 0; tile < 16; ++tile) {
        const int kbase = tile * 64;
        __syncthreads();
        {
            f16x8 a0 = *(const f16x8*)(khp + kgrow + (size_t)kbase * 64);
            f16x8 a1 = *(const f16x8*)(khp + kgrow + (size_t)kbase * 64 + 8);
            f16x8 a2 = *(const f16x8*)(klp + kgrow + (size_t)kbase * 64);
            f16x8 a3 = *(const f16x8*)(klp + kgrow + (size_t)kbase * 64 + 8);
            f16x8 a4 = *(const f16x8*)(vth + vgrow + kbase);
            f16x8 a5 = *(const f16x8*)(vth + vgrow + kbase + 8);
            f16x8 a6 = *(const f16x8*)(vtl + vgrow + kbase);
            f16x8 a7 = *(const f16x8*)(vtl + vgrow + kbase + 8);
            const int rb = srow * 128;
            *(f16x8*)(lds + KH_OFF + rb + swz0) = a0;
            *(f16x8*)(lds + KH_OFF + rb + swz1) = a1;
            *(f16x8*)(lds + KL_OFF + rb + swz0) = a2;
            *(f16x8*)(lds + KL_OFF + rb + swz1) = a3;
            *(f16x8*)(lds + VH_OFF + rb + swz0) = a4;
            *(f16x8*)(lds + VH_OFF + rb + swz1) = a5;
            *(f16x8*)(lds + VL_OFF + rb + swz0) = a6;
            *(f16x8*)(lds + VL_OFF + rb + swz1) = a7;
        }
        __syncthreads();

        // ---- S^T = K * Q^T  (3 f16 split products) ----
        f32x16 s0, s1;
        #pragma unroll
        for (int i = 0; i < 16; ++i) { s0[i] = 0.0f; s1[i] = 0.0f; }
        #pragma unroll
        for (int ks = 0; ks < 4; ++ks) {
            const int dchunk = ks * 2 + lhalf;
            {
                const int kr = l31;
                const int a = KH_OFF + kr * 128 + ((dchunk ^ (kr & 7)) << 4);
                f16x8 ah = *(const f16x8*)(lds + a);
                f16x8 al = *(const f16x8*)(lds + a + 8192);
                s0 = __builtin_amdgcn_mfma_f32_32x32x16_f16(ah, Qh[ks], s0, 0, 0, 0);
                s0 = __builtin_amdgcn_mfma_f32_32x32x16_f16(ah, Ql[ks], s0, 0, 0, 0);
                s0 = __builtin_amdgcn_mfma_f32_32x32x16_f16(al, Qh[ks], s0, 0, 0, 0);
            }
            {
                const int kr = 32 + l31;
                const int a = KH_OFF + kr * 128 + ((dchunk ^ (kr & 7)) << 4);
                f16x8 ah = *(const f16x8*)(lds + a);
                f16x8 al = *(const f16x8*)(lds + a + 8192);
                s1 = __builtin_amdgcn_mfma_f32_32x32x16_f16(ah, Qh[ks], s1, 0, 0, 0);
                s1 = __builtin_amdgcn_mfma_f32_32x32x16_f16(ah, Ql[ks], s1, 0, 0, 0);
                s1 = __builtin_amdgcn_mfma_f32_32x32x16_f16(al, Qh[ks], s1, 0, 0, 0);
            }
        }

        // ---- fake-quant scores + online softmax (row q = l31, halves share q) ----
        float sq[32];
        float mloc = -1e30f;
        #pragma unroll
        for (int r = 0; r < 16; ++r) {
            float raw0 = s0[r] * 0.125f;
            float qv0 = raw0 / s_at + zp_at;
            qv0 = fminf(fmaxf(qv0, 0.0f), QMAXF);
            float v0 = (rintf(qv0) - zp_at) * s_at;
            float raw1 = s1[r] * 0.125f;
            float qv1 = raw1 / s_at + zp_at;
            qv1 = fminf(fmaxf(qv1, 0.0f), QMAXF);
            float v1 = (rintf(qv1) - zp_at) * s_at;
            sq[r] = v0; sq[16 + r] = v1;
            mloc = fmaxf(mloc, fmaxf(v0, v1));
        }
        mloc = fmaxf(mloc, __shfl_xor(mloc, 32));
        float mnew = fmaxf(m_run, mloc);
        float resc = __expf(m_run - mnew);
        float psum = 0.0f;
        #pragma unroll
        for (int i = 0; i < 32; ++i) { sq[i] = __expf(sq[i] - mnew); psum += sq[i]; }
        psum += __shfl_xor(psum, 32);
        l_run = l_run * resc + psum;
        m_run = mnew;
        #pragma unroll
        for (int r = 0; r < 16; ++r) {
            int qr = (r & 3) + 8 * (r >> 2) + 4 * lhalf;
            float f = __shfl(resc, qr);
            o0[r] *= f; o1[r] *= f;
        }

        // ---- pack P hi/lo, write to per-wave P LDS ----
        const int pbase = P_OFF + w * 8192;
        #pragma unroll
        for (int sub = 0; sub < 2; ++sub) {
            #pragma unroll
            for (int rg = 0; rg < 4; ++rg) {
                f16x4 h4, l4;
                #pragma unroll
                for (int e = 0; e < 4; ++e) {
                    float pv = sq[sub * 16 + rg * 4 + e];
                    _Float16 hi = (_Float16)pv;
                    h4[e] = hi;
                    l4[e] = (_Float16)(pv - (float)hi);
                }
                int key0 = sub * 32 + 8 * rg + 4 * lhalf;
                int addr = (l31 * 128 + key0 * 2) ^ ((l31 & 7) << 4);
                *(f16x4*)(lds + pbase + addr) = h4;
                *(f16x4*)(lds + pbase + 4096 + addr) = l4;
            }
        }

        // ---- O += P * V  (3 f16 split products) ----
        #pragma unroll
        for (int ks = 0; ks < 4; ++ks) {
            const int kch = ks * 2 + lhalf;
            const int paddr = l31 * 128 + ((kch ^ (l31 & 7)) << 4);
            f16x8 pa = *(const f16x8*)(lds + pbase + paddr);
            f16x8 pb = *(const f16x8*)(lds + pbase + 4096 + paddr);
            {
                const int dd = l31;
                const int va = VH_OFF + dd * 128 + ((kch ^ (dd & 7)) << 4);
                f16x8 vh = *(const f16x8*)(lds + va);
                f16x8 vl = *(const f16x8*)(lds + va + 8192);
                o0 = __builtin_amdgcn_mfma_f32_32x32x16_f16(pa, vh, o0, 0, 0, 0);
                o0 = __builtin_amdgcn_mfma_f32_32x32x16_f16(pa, vl, o0, 0, 0, 0);
                o0 = __builtin_amdgcn_mfma_f32_32x32x16_f16(pb, vh, o0, 0, 0, 0);
            }
            {
                const int dd = 32 + l31;
                const int va = VH_OFF + dd * 128 + ((kch ^ (dd & 7)) << 4);
                f16x8 vh = *(const f16x8*)(lds + va);
                f16x8 vl = *(const f16x8*)(lds + va + 8192);
                o1 = __builtin_amdgcn_mfma_f32_32x32x16_f16(pa, vh, o1, 0, 0, 0);
                o1 = __builtin_amdgcn_mfma_f32_32x32x16_f16(pa, vl, o1, 0, 0, 0);
                o1 = __builtin_amdgcn_mfma_f32_32x32x16_f16(pb, vh, o1, 0, 0, 0);
            }
        }
    }

    // ---- epilogue: /l, proj-activation fake-quant, write bf16-int ----
    float inv = 1.0f / l_run;
    #pragma unroll
    for (int r = 0; r < 16; ++r) {
        int qr = (r & 3) + 8 * (r >> 2) + 4 * lhalf;
        float fi = __shfl(inv, qr);
        int tok = qt * 128 + w * 32 + qr;
        size_t rowbase = ((size_t)b * Ss + tok) * Ee + h * Dd;
        {
            float val = o0[r] * fi;
            float qv = val / s_ap + zp_ap;
            qv = fminf(fmaxf(qv, 0.0f), QMAXF);
            outq[rowbase + l31] = f2bf_exact(rintf(qv) - zp_ap);
        }
        {
            float val = o1[r] * fi;
            float qv = val / s_ap + zp_ap;
            qv = fminf(fmaxf(qv, 0.0f), QMAXF);
            outq[rowbase + 32 + l31] = f2bf_exact(rintf(qv) - zp_ap);
        }
    }
}

extern "C" void kernel_launch(void* const* d_in, const int* in_sizes, int n_in,
                              void* d_out, int out_size, void* d_ws, size_t ws_size,
                              hipStream_t stream) {
    const float* x           = (const float*)d_in[0];
    const float* W_qkv       = (const float*)d_in[1];
    const float* b_qkv       = (const float*)d_in[2];
    const float* W_proj      = (const float*)d_in[3];
    const float* b_proj      = (const float*)d_in[4];
    const float* s_act_qkv   = (const float*)d_in[5];
    const float* zp_act_qkv  = (const float*)d_in[6];
    const float* s_w_qkv     = (const float*)d_in[7];
    const float* zp_w_qkv    = (const float*)d_in[8];
    const float* s_attn      = (const float*)d_in[9];
    const float* zp_attn     = (const float*)d_in[10];
    const float* s_act_proj  = (const float*)d_in[11];
    const float* zp_act_proj = (const float*)d_in[12];
    const float* s_w_proj    = (const float*)d_in[13];
    const float* zp_w_proj   = (const float*)d_in[14];

    // workspace layout (80 MB):
    // 0:   xq (8MB)  -> reused later as outq (8MB)
    // 8:   wqq (6MB)
    // 14:  wpq (2MB)
    // 16:  qh (8MB)  24: ql (8MB)  32: kh (8MB)  40: kl (8MB)   (f16 planes [64][1024][64])
    // 48:  vb fp32 (16MB) [64][1024][64]
    // 64:  vth (8MB) 72: vtl (8MB)  (f16 planes [64][64][1024])
    char* ws = (char*)d_ws;
    unsigned short* xq   = (unsigned short*)(ws);
    unsigned short* outq = (unsigned short*)(ws);
    unsigned short* wqq  = (unsigned short*)(ws + ((size_t)8 << 20));
    unsigned short* wpq  = (unsigned short*)(ws + ((size_t)14 << 20));
    _Float16* qh         = (_Float16*)(ws + ((size_t)16 << 20));
    _Float16* ql         = (_Float16*)(ws + ((size_t)24 << 20));
    _Float16* kh         = (_Float16*)(ws + ((size_t)32 << 20));
    _Float16* kl         = (_Float16*)(ws + ((size_t)40 << 20));
    float* vb            = (float*)(ws + ((size_t)48 << 20));
    _Float16* vth        = (_Float16*)(ws + ((size_t)64 << 20));
    _Float16* vtl        = (_Float16*)(ws + ((size_t)72 << 20));

    quant_act<<<1024, 256, 0, stream>>>(x, xq, s_act_qkv, zp_act_qkv, Mm * Ee);
    quant_w<<<768, 256, 0, stream>>>(W_qkv, wqq, s_w_qkv, zp_w_qkv, F3 * Ee);
    quant_w<<<256, 256, 0, stream>>>(W_proj, wpq, s_w_proj, zp_w_proj, Ee * Ee);
    gemm_fq<0><<<768, 256, 0, stream>>>(xq, wqq, s_act_qkv, s_w_qkv, b_qkv,
                                        vb, qh, ql, kh, kl, 24);
    vtrans<<<1024, 256, 0, stream>>>(vb, vth, vtl);
    attn_mfma<<<512, 256, 0, stream>>>(qh, ql, kh, kl, vth, vtl,
                                       s_attn, zp_attn, s_act_proj, zp_act_proj, outq);
    gemm_fq<1><<<256, 256, 0, stream>>>(outq, wpq, s_act_proj, s_w_proj, b_proj,
                                        (float*)d_out, nullptr, nullptr, nullptr, nullptr, 8);
}

// Round 4
// 174.707 us; speedup vs baseline: 5.9132x; 1.1058x over previous
//
#include <hip/hip_runtime.h>
#include <hip/hip_bf16.h>
#include <stdint.h>

typedef __attribute__((ext_vector_type(8))) short short8;
typedef __attribute__((ext_vector_type(4))) float f32x4;
typedef __attribute__((ext_vector_type(16))) float f32x16;
typedef _Float16 f16x8 __attribute__((ext_vector_type(8)));
typedef _Float16 f16x4 __attribute__((ext_vector_type(4)));
typedef unsigned int u32x4 __attribute__((ext_vector_type(4)));

#define QMAXF 255.0f
#define MFMA_F16(a, b, c) __builtin_amdgcn_mfma_f32_32x32x16_f16(a, b, c, 0, 0, 0)

constexpr int Bb = 4, Ss = 1024, Ee = 1024, Hh = 16, Dd = 64;
constexpr int Mm = Bb * Ss;   // 4096
constexpr int F3 = 3 * Ee;    // 3072
constexpr int Kk = Ee;        // 1024

__device__ __forceinline__ unsigned short f2bf_exact(float f) {
    return (unsigned short)(__float_as_uint(f) >> 16);
}

__device__ __forceinline__ void gl_lds16(const void* g, void* l) {
    __builtin_amdgcn_global_load_lds((const __attribute__((address_space(1))) unsigned int*)g,
                                     (__attribute__((address_space(3))) unsigned int*)l, 16, 0, 0);
}

__global__ void quant_act(const float* __restrict__ x, unsigned short* __restrict__ out,
                          const float* __restrict__ sp, const float* __restrict__ zpp, int n) {
    float s = sp[0], zp = zpp[0];
    for (int i = blockIdx.x * blockDim.x + threadIdx.x; i < n; i += gridDim.x * blockDim.x) {
        float q = x[i] / s + zp;
        q = fminf(fmaxf(q, 0.0f), QMAXF);
        out[i] = f2bf_exact(rintf(q) - zp);
    }
}

__global__ void quant_w(const float* __restrict__ W, unsigned short* __restrict__ out,
                        const float* __restrict__ sv, const float* __restrict__ zv, int n) {
    for (int i = blockIdx.x * blockDim.x + threadIdx.x; i < n; i += gridDim.x * blockDim.x) {
        int r = i >> 10;
        float s = sv[r], zp = zv[r];
        float q = W[i] / s + zp;
        q = fminf(fmaxf(q, 0.0f), QMAXF);
        out[i] = f2bf_exact(rintf(q) - zp);
    }
}

// C[m][n] = s_a*s_w[n]*sum_k A[m][k]*Bw[n][k] + bias[n]  (bf16 integer MFMA, exact)
// MODE 0: q,k -> f16 hi/lo planes [BH][S][D]; v -> V^T hi/lo planes [BH][D][S]
// MODE 1: fp32 [M][1024] to o0
template<int MODE>
__global__ __launch_bounds__(256)
void gemm_fq(const unsigned short* __restrict__ A,
             const unsigned short* __restrict__ Bw,
             const float* __restrict__ sa_p,
             const float* __restrict__ sw_v,
             const float* __restrict__ bias_v,
             float* __restrict__ o0,
             _Float16* __restrict__ qhp, _Float16* __restrict__ qlp,
             _Float16* __restrict__ khp, _Float16* __restrict__ klp,
             _Float16* __restrict__ vth, _Float16* __restrict__ vtl,
             int ntiles) {
    __shared__ unsigned short At[128][32];
    __shared__ unsigned short Bt[128][32];
    const int t = threadIdx.x;
    // bijective XCD swizzle (gridDim divisible by 8)
    const int nwg = gridDim.x;
    const int swz = (blockIdx.x & 7) * (nwg >> 3) + (blockIdx.x >> 3);
    const int tile_m = (swz / ntiles) * 128;
    const int tile_n = (swz % ntiles) * 128;
    const int lane = t & 63, wid = t >> 6;
    const int wr = wid >> 1, wc = wid & 1;
    const float sa = sa_p[0];

    // staging: 16 issues of 1024B (A: 0-7, B: 8-15); wave w owns issues 4w..4w+3
    const unsigned short* gsrc[4];
    char* ldst[4];
    #pragma unroll
    for (int i = 0; i < 4; ++i) {
        int q = wid * 4 + i;
        int rowq = (q & 7) * 16 + (lane >> 2);
        int colq = (lane & 3) * 8;
        if (q < 8) {
            gsrc[i] = A + (size_t)(tile_m + rowq) * Kk + colq;
            ldst[i] = (char*)At + q * 1024;
        } else {
            gsrc[i] = Bw + (size_t)(tile_n + rowq) * Kk + colq;
            ldst[i] = (char*)Bt + (q - 8) * 1024;
        }
    }

    f32x4 acc[4][4];
    #pragma unroll
    for (int i = 0; i < 4; ++i)
        #pragma unroll
        for (int j = 0; j < 4; ++j)
            #pragma unroll
            for (int e = 0; e < 4; ++e) acc[i][j][e] = 0.0f;

    const int NKT = Kk / 32;
    for (int kt = 0; kt < NKT; ++kt) {
        __syncthreads();
        #pragma unroll
        for (int i = 0; i < 4; ++i)
            gl_lds16(gsrc[i] + kt * 32, ldst[i]);
        __syncthreads();

        const int kq = (lane >> 4) * 8;
        const int rowA = wr * 64 + (lane & 15);
        const int rowB = wc * 64 + (lane & 15);
        short8 af[4], bfr[4];
        #pragma unroll
        for (int i = 0; i < 4; ++i) af[i] = *(const short8*)&At[rowA + i * 16][kq];
        #pragma unroll
        for (int j = 0; j < 4; ++j) bfr[j] = *(const short8*)&Bt[rowB + j * 16][kq];
        #pragma unroll
        for (int i = 0; i < 4; ++i)
            #pragma unroll
            for (int j = 0; j < 4; ++j)
                acc[i][j] = __builtin_amdgcn_mfma_f32_16x16x32_bf16(af[i], bfr[j], acc[i][j], 0, 0, 0);
    }

    // C/D layout: col = lane&15, row = (lane>>4)*4 + reg
    const int lr4 = (lane >> 4) * 4;
    const int lc = lane & 15;
    #pragma unroll
    for (int j = 0; j < 4; ++j) {
        int n = tile_n + wc * 64 + j * 16 + lc;
        float sw = sw_v[n] * sa;
        float bv = bias_v[n];
        #pragma unroll
        for (int i = 0; i < 4; ++i) {
            int mbase = tile_m + wr * 64 + i * 16 + lr4;
            if (MODE == 0) {
                int which = n >> 10, hh = (n >> 6) & 15, d = n & 63;
                int bi = mbase >> 10, si0 = mbase & 1023;
                if (which == 2) {
                    f16x4 hv, lv;
                    #pragma unroll
                    for (int r = 0; r < 4; ++r) {
                        float val = acc[i][j][r] * sw + bv;
                        _Float16 hi = (_Float16)val;
                        hv[r] = hi;
                        lv[r] = (_Float16)(val - (float)hi);
                    }
                    size_t base = (((size_t)(bi * Hh + hh)) * Dd + d) * Ss + si0;
                    *(f16x4*)(vth + base) = hv;
                    *(f16x4*)(vtl + base) = lv;
                } else {
                    #pragma unroll
                    for (int r = 0; r < 4; ++r) {
                        float val = acc[i][j][r] * sw + bv;
                        size_t idx = (((size_t)(bi * Hh + hh)) * Ss + si0 + r) * Dd + d;
                        _Float16 hi = (_Float16)val;
                        _Float16 lo = (_Float16)(val - (float)hi);
                        if (which == 0) { qhp[idx] = hi; qlp[idx] = lo; }
                        else            { khp[idx] = hi; klp[idx] = lo; }
                    }
                }
            } else {
                #pragma unroll
                for (int r = 0; r < 4; ++r) {
                    float val = acc[i][j][r] * sw + bv;
                    o0[(size_t)(mbase + r) * Ee + n] = val;
                }
            }
        }
    }
}

// Fused flash attention, f16 hi/lo split MFMA; integer-domain softmax with
// defer-max; in-register P fragments via cvt_pkrtz + permlane32_swap.
__global__ __launch_bounds__(256, 2)
void attn_mfma(const _Float16* __restrict__ qhp, const _Float16* __restrict__ qlp,
               const _Float16* __restrict__ khp, const _Float16* __restrict__ klp,
               const _Float16* __restrict__ vth, const _Float16* __restrict__ vtl,
               const float* __restrict__ s_at_p, const float* __restrict__ zp_at_p,
               const float* __restrict__ s_ap_p, const float* __restrict__ zp_ap_p,
               unsigned short* __restrict__ outq) {
    __shared__ uint4 lds4[65536 / 16];   // 2 x 32KB double buffer
    char* lds = (char*)lds4;

    const int t = threadIdx.x;
    const int lane = t & 63;
    const int w = t >> 6;
    const int l31 = lane & 31;
    const int lhalf = lane >> 5;
    const int bh = blockIdx.x >> 3;
    const int qt = blockIdx.x & 7;
    const int b = bh >> 4, h = bh & 15;

    const float s_at = s_at_p[0], zp_at = zp_at_p[0];
    const float s_ap = s_ap_p[0], zp_ap = zp_ap_p[0];
    const float c1 = 0.125f / s_at;        // raw score -> q units (one fma)

    // Q fragments (B-operand): lane holds Q[q0+l31][ks*16 + lhalf*8 + 0..7]
    const int qrow = qt * 128 + w * 32 + l31;
    const size_t qbase = ((size_t)bh * Ss + qrow) * Dd;
    f16x8 Qh[4], Ql[4];
    #pragma unroll
    for (int ks = 0; ks < 4; ++ks) {
        int dd = ks * 16 + lhalf * 8;
        Qh[ks] = *(const f16x8*)(qhp + qbase + dd);
        Ql[ks] = *(const f16x8*)(qlp + qbase + dd);
    }

    f32x16 o0, o1;
    #pragma unroll
    for (int i = 0; i < 16; ++i) { o0[i] = 0.0f; o1[i] = 0.0f; }
    float m_run = -1e30f, l_run = 0.0f;

    // staging addressing: thread covers chunks {sch, sch+1} of row srow, 4 planes
    const int srow = t >> 2;              // 0..63
    const int sch = (t & 3) * 2;          // 0,2,4,6
    const int swz0 = ((sch    ) ^ (srow & 7)) << 4;
    const int swz1 = ((sch + 1) ^ (srow & 7)) << 4;
    const int rb = srow * 128;
    const size_t kgrow = ((size_t)bh * Ss + srow) * Dd + sch * 8;
    const size_t vgrow = ((size_t)bh * Dd + srow) * Ss + sch * 8;

    f16x8 st[8];
    #define STAGE_LOAD(tl) {                                            \
        const size_t ko = kgrow + (size_t)(tl) * 64 * 64;               \
        const size_t vo = vgrow + (size_t)(tl) * 64;                    \
        st[0] = *(const f16x8*)(khp + ko);                              \
        st[1] = *(const f16x8*)(khp + ko + 8);                          \
        st[2] = *(const f16x8*)(klp + ko);                              \
        st[3] = *(const f16x8*)(klp + ko + 8);                          \
        st[4] = *(const f16x8*)(vth + vo);                              \
        st[5] = *(const f16x8*)(vth + vo + 8);                          \
        st[6] = *(const f16x8*)(vtl + vo);                              \
        st[7] = *(const f16x8*)(vtl + vo + 8);                          \
    }
    #define STAGE_WRITE(bsel) {                                         \
        char* base = lds + (bsel) * 32768;                              \
        *(f16x8*)(base +     0 + rb + swz0) = st[0];                    \
        *(f16x8*)(base +     0 + rb + swz1) = st[1];                    \
        *(f16x8*)(base +  8192 + rb + swz0) = st[2];                    \
        *(f16x8*)(base +  8192 + rb + swz1) = st[3];                    \
        *(f16x8*)(base + 16384 + rb + swz0) = st[4];                    \
        *(f16x8*)(base + 16384 + rb + swz1) = st[5];                    \
        *(f16x8*)(base + 24576 + rb + swz0) = st[6];                    \
        *(f16x8*)(base + 24576 + rb + swz1) = st[7];                    \
    }

    STAGE_LOAD(0);
    STAGE_WRITE(0);
    __syncthreads();

    for (int tile = 0; tile < 16; ++tile) {
        const int bsel = tile & 1;
        char* B = lds + bsel * 32768;
        if (tile < 15) STAGE_LOAD(tile + 1);

        // ---- S^T = K * Q^T (3 split products) ----
        f32x16 s0, s1;
        #pragma unroll
        for (int i = 0; i < 16; ++i) { s0[i] = 0.0f; s1[i] = 0.0f; }
        __builtin_amdgcn_s_setprio(1);
        #pragma unroll
        for (int ks = 0; ks < 4; ++ks) {
            const int dchunk = ks * 2 + lhalf;
            {
                const int kr = l31;
                const char* a = B + kr * 128 + ((dchunk ^ (kr & 7)) << 4);
                f16x8 ah = *(const f16x8*)(a);
                f16x8 al = *(const f16x8*)(a + 8192);
                s0 = MFMA_F16(ah, Qh[ks], s0);
                s0 = MFMA_F16(ah, Ql[ks], s0);
                s0 = MFMA_F16(al, Qh[ks], s0);
            }
            {
                const int kr = 32 + l31;
                const char* a = B + kr * 128 + ((dchunk ^ (kr & 7)) << 4);
                f16x8 ah = *(const f16x8*)(a);
                f16x8 al = *(const f16x8*)(a + 8192);
                s1 = MFMA_F16(ah, Qh[ks], s1);
                s1 = MFMA_F16(ah, Ql[ks], s1);
                s1 = MFMA_F16(al, Qh[ks], s1);
            }
        }
        __builtin_amdgcn_s_setprio(0);

        // ---- integer-domain fake-quant + online softmax ----
        float rq[32];
        #pragma unroll
        for (int r = 0; r < 16; ++r) {
            float q0 = fmaf(s0[r], c1, zp_at);
            q0 = fminf(fmaxf(q0, 0.0f), QMAXF);
            rq[r] = rintf(q0);
            float q1 = fmaf(s1[r], c1, zp_at);
            q1 = fminf(fmaxf(q1, 0.0f), QMAXF);
            rq[16 + r] = rintf(q1);
        }
        float mx[16];
        #pragma unroll
        for (int i = 0; i < 16; ++i) mx[i] = fmaxf(rq[2 * i], rq[2 * i + 1]);
        #pragma unroll
        for (int i = 0; i < 8; ++i) mx[i] = fmaxf(mx[i], mx[i + 8]);
        #pragma unroll
        for (int i = 0; i < 4; ++i) mx[i] = fmaxf(mx[i], mx[i + 4]);
        float mloc = fmaxf(fmaxf(mx[0], mx[1]), fmaxf(mx[2], mx[3]));
        mloc = fmaxf(mloc, __shfl_xor(mloc, 32));

        if (!__all(mloc - m_run <= 64.0f)) {   // defer-max: rare rescale
            float mnew = fmaxf(m_run, mloc);
            float fac = __expf((m_run - mnew) * s_at);
            l_run *= fac;
            #pragma unroll
            for (int r = 0; r < 16; ++r) {
                int qr = (r & 3) + 8 * (r >> 2) + 4 * lhalf;
                float f = __shfl(fac, qr);
                o0[r] *= f; o1[r] *= f;
            }
            m_run = mnew;
        }

        float p[32];
        float psum = 0.0f;
        #pragma unroll
        for (int i = 0; i < 32; ++i) {
            p[i] = __expf((rq[i] - m_run) * s_at);
            psum += p[i];
        }
        psum += __shfl_xor(psum, 32);
        l_run += psum;

        // ---- pack P hi/lo + permlane32_swap into A-fragments ----
        unsigned int wH[16], wL[16];
        #pragma unroll
        for (int wi = 0; wi < 16; ++wi) {
            float a = p[2 * wi], bb2 = p[2 * wi + 1];
            auto hh2 = __builtin_amdgcn_cvt_pkrtz(a, bb2);          // __fp16 x2
            wH[wi] = __builtin_bit_cast(unsigned int, hh2);
            float ha = (float)hh2[0], hb = (float)hh2[1];
            auto ll2 = __builtin_amdgcn_cvt_pkrtz(a - ha, bb2 - hb);
            wL[wi] = __builtin_bit_cast(unsigned int, ll2);
        }
        f16x8 fragH[4], fragL[4];
        #pragma unroll
        for (int ks = 0; ks < 4; ++ks) {
            auto h0 = __builtin_amdgcn_permlane32_swap(wH[4 * ks], wH[4 * ks + 2], false, false);
            auto h1 = __builtin_amdgcn_permlane32_swap(wH[4 * ks + 1], wH[4 * ks + 3], false, false);
            fragH[ks] = __builtin_bit_cast(f16x8, (u32x4){h0[0], h1[0], h0[1], h1[1]});
            auto g0 = __builtin_amdgcn_permlane32_swap(wL[4 * ks], wL[4 * ks + 2], false, false);
            auto g1 = __builtin_amdgcn_permlane32_swap(wL[4 * ks + 1], wL[4 * ks + 3], false, false);
            fragL[ks] = __builtin_bit_cast(f16x8, (u32x4){g0[0], g1[0], g0[1], g1[1]});
        }

        // ---- O += P * V (3 split products) ----
        __builtin_amdgcn_s_setprio(1);
        #pragma unroll
        for (int ks = 0; ks < 4; ++ks) {
            const int kch = ks * 2 + lhalf;
            {
                const int dd = l31;
                const char* va = B + 16384 + dd * 128 + ((kch ^ (dd & 7)) << 4);
                f16x8 vh = *(const f16x8*)(va);
                f16x8 vl = *(const f16x8*)(va + 8192);
                o0 = MFMA_F16(fragH[ks], vh, o0);
                o0 = MFMA_F16(fragH[ks], vl, o0);
                o0 = MFMA_F16(fragL[ks], vh, o0);
            }
            {
                const int dd = 32 + l31;
                const char* va = B + 16384 + dd * 128 + ((kch ^ (dd & 7)) << 4);
                f16x8 vh = *(const f16x8*)(va);
                f16x8 vl = *(const f16x8*)(va + 8192);
                o1 = MFMA_F16(fragH[ks], vh, o1);
                o1 = MFMA_F16(fragH[ks], vl, o1);
                o1 = MFMA_F16(fragL[ks], vh, o1);
            }
        }
        __builtin_amdgcn_s_setprio(0);

        if (tile < 15) STAGE_WRITE(bsel ^ 1);
        __syncthreads();
    }

    // ---- epilogue: /l, proj-activation fake-quant, write bf16-int ----
    float inv = 1.0f / l_run;
    #pragma unroll
    for (int r = 0; r < 16; ++r) {
        int qr = (r & 3) + 8 * (r >> 2) + 4 * lhalf;
        float fi = __shfl(inv, qr);
        int tok = qt * 128 + w * 32 + qr;
        size_t rowbase = ((size_t)b * Ss + tok) * Ee + h * Dd;
        {
            float qv = (o0[r] * fi) / s_ap + zp_ap;
            qv = fminf(fmaxf(qv, 0.0f), QMAXF);
            outq[rowbase + l31] = f2bf_exact(rintf(qv) - zp_ap);
        }
        {
            float qv = (o1[r] * fi) / s_ap + zp_ap;
            qv = fminf(fmaxf(qv, 0.0f), QMAXF);
            outq[rowbase + 32 + l31] = f2bf_exact(rintf(qv) - zp_ap);
        }
    }
}

extern "C" void kernel_launch(void* const* d_in, const int* in_sizes, int n_in,
                              void* d_out, int out_size, void* d_ws, size_t ws_size,
                              hipStream_t stream) {
    const float* x           = (const float*)d_in[0];
    const float* W_qkv       = (const float*)d_in[1];
    const float* b_qkv       = (const float*)d_in[2];
    const float* W_proj      = (const float*)d_in[3];
    const float* b_proj      = (const float*)d_in[4];
    const float* s_act_qkv   = (const float*)d_in[5];
    const float* zp_act_qkv  = (const float*)d_in[6];
    const float* s_w_qkv     = (const float*)d_in[7];
    const float* zp_w_qkv    = (const float*)d_in[8];
    const float* s_attn      = (const float*)d_in[9];
    const float* zp_attn     = (const float*)d_in[10];
    const float* s_act_proj  = (const float*)d_in[11];
    const float* zp_act_proj = (const float*)d_in[12];
    const float* s_w_proj    = (const float*)d_in[13];
    const float* zp_w_proj   = (const float*)d_in[14];

    // ws layout (64MB): 0 xq/outq(8) | 8 wqq(6) | 14 wpq(2) | 16 qh(8) | 24 ql(8)
    //                   32 kh(8) | 40 kl(8) | 48 vth(8) | 56 vtl(8)
    char* ws = (char*)d_ws;
    unsigned short* xq   = (unsigned short*)(ws);
    unsigned short* outq = (unsigned short*)(ws);
    unsigned short* wqq  = (unsigned short*)(ws + ((size_t)8 << 20));
    unsigned short* wpq  = (unsigned short*)(ws + ((size_t)14 << 20));
    _Float16* qh         = (_Float16*)(ws + ((size_t)16 << 20));
    _Float16* ql         = (_Float16*)(ws + ((size_t)24 << 20));
    _Float16* kh         = (_Float16*)(ws + ((size_t)32 << 20));
    _Float16* kl         = (_Float16*)(ws + ((size_t)40 << 20));
    _Float16* vth        = (_Float16*)(ws + ((size_t)48 << 20));
    _Float16* vtl        = (_Float16*)(ws + ((size_t)56 << 20));

    quant_act<<<1024, 256, 0, stream>>>(x, xq, s_act_qkv, zp_act_qkv, Mm * Ee);
    quant_w<<<768, 256, 0, stream>>>(W_qkv, wqq, s_w_qkv, zp_w_qkv, F3 * Ee);
    quant_w<<<256, 256, 0, stream>>>(W_proj, wpq, s_w_proj, zp_w_proj, Ee * Ee);
    gemm_fq<0><<<768, 256, 0, stream>>>(xq, wqq, s_act_qkv, s_w_qkv, b_qkv,
                                        nullptr, qh, ql, kh, kl, vth, vtl, 24);
    attn_mfma<<<512, 256, 0, stream>>>(qh, ql, kh, kl, vth, vtl,
                                       s_attn, zp_attn, s_act_proj, zp_act_proj, outq);
    gemm_fq<1><<<256, 256, 0, stream>>>(outq, wpq, s_act_proj, s_w_proj, b_proj,
                                        (float*)d_out, nullptr, nullptr, nullptr, nullptr,
                                        nullptr, nullptr, 8);
}